// Round 1
// baseline (1321.645 us; speedup 1.0000x reference)
//
#include <hip/hip_runtime.h>

// ---------------------------------------------------------------------------
// BiLstmCrf: bidirectional lattice-LSTM + CRF NLL, reduced to one scalar.
//
// Pipeline (all on `stream`):
//   1. emb_gemm_kernel x6 : Xg = X@Wcx+bc (per dir, reverse for r),
//                           Xl = X@Wlx+bl, Wg = Xw@Wwx+bw
//   2. lattice_kernel     : 32 WGs (one per (batch,dir)), 512 thr.
//                           Wch columns in VGPRs (f32), Wwh/Wlc in VGPRs (f16
//                           packed). h/c history in global ws; h_cur in LDS.
//   3. emb_gemm_kernel    : logits = feats @ dense_W + dense_b
//   4. crf_kernel         : per-batch alpha recursion + gold score
//   5. finalize_kernel    : mean over batches -> d_out[0]
// ---------------------------------------------------------------------------

typedef _Float16 f16x2 __attribute__((ext_vector_type(2)));

__device__ __forceinline__ float sigm(float x) { return 1.f / (1.f + __expf(-x)); }

// out[row][j] = sum_k emb[idx(row)][k] * W[k][j] + bias[j]
// idx==nullptr -> row indexes emb directly. rev -> time-reversed gather.
__global__ void emb_gemm_kernel(const float* __restrict__ emb,
                                const int* __restrict__ idx,
                                const float* __restrict__ W,
                                const float* __restrict__ bias,
                                float* __restrict__ out,
                                int K, int J, int rowsTotal, int Sdim, int rev)
{
    __shared__ __align__(16) float xs[16 * 256];
    const int r0 = blockIdx.x * 16;
    for (int rr = 0; rr < 16; rr++) {
        const int row = r0 + rr;
        const float* src = nullptr;
        if (row < rowsTotal) {
            if (idx) {
                const int bb = row / Sdim;
                const int tt = row - bb * Sdim;
                const int tsrc = rev ? (Sdim - 1 - tt) : tt;
                src = emb + (size_t)idx[bb * Sdim + tsrc] * K;
            } else {
                src = emb + (size_t)row * K;
            }
        }
        for (int k = threadIdx.x; k < K; k += blockDim.x)
            xs[rr * K + k] = src ? src[k] : 0.f;
    }
    __syncthreads();
    const int j = threadIdx.x;   // blockDim.x == J
    float acc[16];
#pragma unroll
    for (int rr = 0; rr < 16; rr++) acc[rr] = 0.f;
    for (int k = 0; k < K; k++) {
        const float w = W[(size_t)k * J + j];
#pragma unroll
        for (int rr = 0; rr < 16; rr++) acc[rr] = fmaf(xs[rr * K + k], w, acc[rr]);
    }
    const float bj = bias[j];
    for (int rr = 0; rr < 16; rr++) {
        const int row = r0 + rr;
        if (row < rowsTotal) out[(size_t)row * J + j] = acc[rr] + bj;
    }
}

// One WG per (batch, dir). 512 threads: tid = kc*128 + jj, kc in [0,4) is the
// k-chunk (32 ks), jj in [0,128) the output column within each gate.
__global__ __launch_bounds__(512, 2)
void lattice_kernel(const float* __restrict__ Xg,    // [2][B*S][512]
                    const float* __restrict__ Xl,    // [2][B*S][128]
                    const float* __restrict__ Wgp,   // [2][B*N][384]
                    const float* __restrict__ Wch_f, const float* __restrict__ Wch_r,
                    const float* __restrict__ Wwh_f, const float* __restrict__ Wwh_r,
                    const float* __restrict__ Wlc_f, const float* __restrict__ Wlc_r,
                    const int* __restrict__ word_begin, const int* __restrict__ word_len,
                    const int* __restrict__ seqlen,
                    float* __restrict__ hist_h,      // [32][129][128]
                    float* __restrict__ hist_c,      // [32][129][128]
                    float* __restrict__ feats)       // [B*S][256]
{
    const int bdid = blockIdx.x;           // 0..31
    const int b = bdid >> 1, dir = bdid & 1;
    const int tid = threadIdx.x;
    const int kc = tid >> 7;
    const int jj = tid & 127;

    const float* Wch = dir ? Wch_r : Wch_f;
    const float* Wwh = dir ? Wwh_r : Wwh_f;
    const float* Wlc = dir ? Wlc_r : Wlc_f;

    // ---- weights into registers -------------------------------------------
    float wch[128];                        // Wch[k][g*128+jj], k in chunk, g in 0..3
    {
        const float* base = Wch + (size_t)(kc * 32) * 512 + jj;
#pragma unroll
        for (int u = 0; u < 32; u++) {
#pragma unroll
            for (int g = 0; g < 4; g++)
                wch[u * 4 + g] = base[(size_t)u * 512 + g * 128];
        }
    }
    f16x2 wwh2[48];                        // Wwh pairs over k, 3 gate-thirds
    {
        const float* base = Wwh + (size_t)(kc * 32) * 384 + jj;
#pragma unroll
        for (int u2 = 0; u2 < 16; u2++) {
#pragma unroll
            for (int g = 0; g < 3; g++) {
                f16x2 v;
                v.x = (_Float16)base[(size_t)(2 * u2) * 384 + g * 128];
                v.y = (_Float16)base[(size_t)(2 * u2 + 1) * 384 + g * 128];
                wwh2[u2 * 3 + g] = v;
            }
        }
    }
    f16x2 wlc2[16];                        // Wlc pairs over k
    {
        const float* base = Wlc + (size_t)(kc * 32) * 128 + jj;
#pragma unroll
        for (int u2 = 0; u2 < 16; u2++) {
            f16x2 v;
            v.x = (_Float16)base[(size_t)(2 * u2) * 128];
            v.y = (_Float16)base[(size_t)(2 * u2 + 1) * 128];
            wlc2[u2] = v;
        }
    }

    // ---- LDS --------------------------------------------------------------
    __shared__ __align__(16) float h_cur[128], c_cur[128];
    __shared__ __align__(16) float part[2048];
    __shared__ __align__(16) float gates[512];       // activated i,f,o,g
    __shared__ __align__(16) f16x2 hb2s[64];         // gathered h_hist[begin] as f16
    __shared__ __align__(16) float cb_s[128];
    __shared__ __align__(16) float cw_s[128];
    __shared__ __align__(16) f16x2 cw2s[64];
    __shared__ __align__(16) float acc_num[128], acc_den[128];
    __shared__ int ev_start[129];
    __shared__ int cnts[128];
    __shared__ int fills[128];
    __shared__ short ev_word[64];
    __shared__ short wbeg[64];

    const int sl = seqlen[b];

    // ---- build per-t word-event schedule ----------------------------------
    if (tid < 128) { cnts[tid] = 0; fills[tid] = 0; }
    __syncthreads();
    int myvalid = 0, myed = 0;
    if (tid < 64) {
        const int bg = word_begin[b * 64 + tid];
        const int ln = word_len[b * 64 + tid];
        int ef = bg + ln; if (ef > 127) ef = 127;       // end = min(begin+len, S-1)
        myvalid = (ef < sl);                             // word_valid
        int bd_, ed_;
        if (dir == 0) { bd_ = bg; ed_ = ef; } else { bd_ = 127 - ef; ed_ = 127 - bg; }
        wbeg[tid] = (short)bd_;
        myed = ed_;
        if (myvalid) atomicAdd(&cnts[ed_], 1);
    }
    __syncthreads();
    if (tid == 0) {
        int run = 0;
        ev_start[0] = 0;
        for (int t = 0; t < 128; t++) { run += cnts[t]; ev_start[t + 1] = run; }
    }
    __syncthreads();
    if (tid < 64 && myvalid) {
        const int pos = atomicAdd(&fills[myed], 1);
        ev_word[ev_start[myed] + pos] = (short)tid;
    }
    float* hh = hist_h + (size_t)bdid * 129 * 128;
    float* ch = hist_c + (size_t)bdid * 129 * 128;
    if (tid < 128) {
        h_cur[tid] = 0.f; c_cur[tid] = 0.f;
        hh[tid] = 0.f;    ch[tid] = 0.f;       // slot 0
    }
    __syncthreads();

    const float* Xg_b = Xg + ((size_t)dir * 2048 + (size_t)b * 128) * 512;
    const float* Xl_b = Xl + ((size_t)dir * 2048 + (size_t)b * 128) * 128;
    const float* Wg_b = Wgp + ((size_t)dir * 1024 + (size_t)b * 64) * 384;

    // ---- main scan --------------------------------------------------------
    for (int t = 0; t < 128; t++) {
        const float xg = Xg_b[(size_t)t * 512 + tid];   // prefetch (used post-barrier)

        // h_prev @ Wch : partial over this thread's k-chunk for 4 gate outputs
        float p0 = 0.f, p1 = 0.f, p2 = 0.f, p3 = 0.f;
        const float* hp = &h_cur[kc * 32];
#pragma unroll
        for (int u = 0; u < 32; u++) {
            const float hv = hp[u];
            p0 = fmaf(wch[u * 4 + 0], hv, p0);
            p1 = fmaf(wch[u * 4 + 1], hv, p1);
            p2 = fmaf(wch[u * 4 + 2], hv, p2);
            p3 = fmaf(wch[u * 4 + 3], hv, p3);
        }
        part[kc * 512 + jj]       = p0;
        part[kc * 512 + 128 + jj] = p1;
        part[kc * 512 + 256 + jj] = p2;
        part[kc * 512 + 384 + jj] = p3;
        __syncthreads();
        {
            const float a = xg + part[tid] + part[512 + tid] + part[1024 + tid] + part[1536 + tid];
            gates[tid] = (tid < 384) ? sigm(a) : tanhf(a);   // i,f,o sigmoid; g tanh
        }
        __syncthreads();

        const int e0 = ev_start[t], e1 = ev_start[t + 1];
        const bool hasw = (e1 > e0);
        if (hasw) {
            if (tid < 128) { acc_num[tid] = 0.f; acc_den[tid] = 0.f; }
            for (int e = e0; e < e1; e++) {
                const int w = ev_word[e];
                if (tid < 128) {
                    const int bg = wbeg[w];
                    const float hbv = hh[(size_t)bg * 128 + tid];
                    cb_s[tid] = ch[(size_t)bg * 128 + tid];
                    ((_Float16*)hb2s)[tid] = (_Float16)hbv;
                }
                __syncthreads();
                {   // hb @ Wwh (f16 weights, fp32 accumulate)
                    const f16x2* hb2 = hb2s + kc * 16;
                    float q0 = 0.f, q1 = 0.f, q2 = 0.f;
#pragma unroll
                    for (int u2 = 0; u2 < 16; u2++) {
                        const f16x2 hv = hb2[u2];
                        const float h0 = (float)hv.x, h1 = (float)hv.y;
                        const f16x2 w0 = wwh2[u2 * 3 + 0];
                        const f16x2 w1 = wwh2[u2 * 3 + 1];
                        const f16x2 w2 = wwh2[u2 * 3 + 2];
                        q0 = fmaf((float)w0.x, h0, q0); q0 = fmaf((float)w0.y, h1, q0);
                        q1 = fmaf((float)w1.x, h0, q1); q1 = fmaf((float)w1.y, h1, q1);
                        q2 = fmaf((float)w2.x, h0, q2); q2 = fmaf((float)w2.y, h1, q2);
                    }
                    part[kc * 512 + jj]       = q0;
                    part[kc * 512 + 128 + jj] = q1;
                    part[kc * 512 + 256 + jj] = q2;
                }
                __syncthreads();
                if (tid < 128) {
                    const float* wgr = Wg_b + (size_t)w * 384;
                    const float wiv = wgr[tid]       + part[tid]       + part[512 + tid]  + part[1024 + tid] + part[1536 + tid];
                    const float wfv = wgr[128 + tid] + part[128 + tid] + part[640 + tid]  + part[1152 + tid] + part[1664 + tid];
                    const float wgv = wgr[256 + tid] + part[256 + tid] + part[768 + tid]  + part[1280 + tid] + part[1792 + tid];
                    const float cwv = sigm(wfv) * cb_s[tid] + sigm(wiv) * tanhf(wgv);
                    cw_s[tid] = cwv;
                    ((_Float16*)cw2s)[tid] = (_Float16)cwv;
                }
                __syncthreads();
                {   // cw @ Wlc
                    const f16x2* cw2 = cw2s + kc * 16;
                    float r = 0.f;
#pragma unroll
                    for (int u2 = 0; u2 < 16; u2++) {
                        const f16x2 cv = cw2[u2];
                        const f16x2 wv = wlc2[u2];
                        r = fmaf((float)wv.x, (float)cv.x, r);
                        r = fmaf((float)wv.y, (float)cv.y, r);
                    }
                    part[kc * 512 + jj] = r;
                }
                __syncthreads();
                if (tid < 128) {
                    float lgv = Xl_b[(size_t)t * 128 + tid]
                              + part[tid] + part[512 + tid] + part[1024 + tid] + part[1536 + tid];
                    lgv = sigm(lgv);
                    const float ew = __expf(lgv);
                    acc_num[tid] = fmaf(ew, cw_s[tid], acc_num[tid]);
                    acc_den[tid] += ew;
                }
                __syncthreads();
            }
        }

        // ---- c/h update ----------------------------------------------------
        if (tid < 128) {
            const float iv = gates[tid], fv = gates[128 + tid];
            const float ov = gates[256 + tid], gv = gates[384 + tid];
            float c_t;
            if (hasw) {
                const float ec = __expf(iv);
                c_t = (ec * gv + acc_num[tid]) / (ec + acc_den[tid]);
            } else {
                c_t = fv * c_cur[tid] + iv * gv;
            }
            const float h_t = ov * tanhf(c_t);
            const bool v = dir ? (t >= 128 - sl) : (t < sl);
            const float hn = v ? h_t : h_cur[tid];
            const float cn = v ? c_t : c_cur[tid];
            h_cur[tid] = hn; c_cur[tid] = cn;
            hh[(size_t)(t + 1) * 128 + tid] = hn;
            ch[(size_t)(t + 1) * 128 + tid] = cn;
            const int s = dir ? (127 - t) : t;
            feats[((size_t)b * 128 + s) * 256 + dir * 128 + tid] = v ? h_t : 0.f;
        }
        __syncthreads();
    }
}

// One WG (64 thr) per batch: gold score + alpha recursion + logZ.
__global__ void crf_kernel(const float* __restrict__ logits,  // [B*S][32]
                           const int* __restrict__ label,     // [B*S]
                           const int* __restrict__ seqlen,
                           const float* __restrict__ T,       // [32][32]
                           float* __restrict__ out_part)      // [B]
{
    const int b = blockIdx.x;
    const int tid = threadIdx.x;   // 64
    __shared__ float Tl[1024];
    __shared__ float alpha[32];
    __shared__ float red[64];
    for (int i = tid; i < 1024; i += 64) Tl[i] = T[i];
    const float* lg = logits + (size_t)b * 128 * 32;
    const int* lab = label + b * 128;
    const int sl = seqlen[b];

    float g = 0.f;
    for (int t = tid; t < 128; t += 64) {
        if (t < sl) {
            g += lg[t * 32 + lab[t]];
            if (t >= 1) g += T[lab[t - 1] * 32 + lab[t]];
        }
    }
    red[tid] = g;
    __syncthreads();
    for (int s2 = 32; s2 > 0; s2 >>= 1) {
        if (tid < s2) red[tid] += red[tid + s2];
        __syncthreads();
    }
    if (tid < 32) alpha[tid] = lg[tid];
    __syncthreads();
    for (int t = 1; t < 128; t++) {
        float nv = 0.f;
        if (tid < 32) {
            float m = -1e30f;
#pragma unroll
            for (int i = 0; i < 32; i++) m = fmaxf(m, alpha[i] + Tl[i * 32 + tid]);
            float s = 0.f;
#pragma unroll
            for (int i = 0; i < 32; i++) s += __expf(alpha[i] + Tl[i * 32 + tid] - m);
            nv = m + __logf(s) + lg[t * 32 + tid];
            if (t >= sl) nv = alpha[tid];
        }
        __syncthreads();
        if (tid < 32) alpha[tid] = nv;
        __syncthreads();
    }
    if (tid == 0) {
        float m = -1e30f;
        for (int i = 0; i < 32; i++) m = fmaxf(m, alpha[i]);
        float s = 0.f;
        for (int i = 0; i < 32; i++) s += __expf(alpha[i] - m);
        out_part[b] = (m + __logf(s)) - red[0];
    }
}

__global__ void finalize_kernel(const float* __restrict__ partb, float* __restrict__ out)
{
    if (threadIdx.x == 0 && blockIdx.x == 0) {
        float s = 0.f;
        for (int i = 0; i < 16; i++) s += partb[i];
        out[0] = s * (1.f / 16.f);
    }
}

extern "C" void kernel_launch(void* const* d_in, const int* in_sizes, int n_in,
                              void* d_out, int out_size, void* d_ws, size_t ws_size,
                              hipStream_t stream)
{
    (void)in_sizes; (void)n_in; (void)out_size; (void)ws_size;
    const int*   char_ids    = (const int*)d_in[0];
    const int*   kb_word_ids = (const int*)d_in[1];
    const int*   word_begin  = (const int*)d_in[2];
    const int*   word_len    = (const int*)d_in[3];
    const int*   label       = (const int*)d_in[4];
    const int*   seqlen      = (const int*)d_in[5];
    const float* char_emb    = (const float*)d_in[6];
    const float* kb_emb      = (const float*)d_in[7];
    const float* dense_W     = (const float*)d_in[8];
    const float* dense_b     = (const float*)d_in[9];
    const float* crf_T       = (const float*)d_in[10];
    const float* f_Wcx = (const float*)d_in[11];
    const float* f_Wch = (const float*)d_in[12];
    const float* f_bc  = (const float*)d_in[13];
    const float* f_Wwx = (const float*)d_in[14];
    const float* f_Wwh = (const float*)d_in[15];
    const float* f_bw  = (const float*)d_in[16];
    const float* f_Wlx = (const float*)d_in[17];
    const float* f_Wlc = (const float*)d_in[18];
    const float* f_bl  = (const float*)d_in[19];
    const float* r_Wcx = (const float*)d_in[20];
    const float* r_Wch = (const float*)d_in[21];
    const float* r_bc  = (const float*)d_in[22];
    const float* r_Wwx = (const float*)d_in[23];
    const float* r_Wwh = (const float*)d_in[24];
    const float* r_bw  = (const float*)d_in[25];
    const float* r_Wlx = (const float*)d_in[26];
    const float* r_Wlc = (const float*)d_in[27];
    const float* r_bl  = (const float*)d_in[28];

    float* ws = (float*)d_ws;
    size_t o = 0;
    float* Xg     = ws + o; o += (size_t)2 * 2048 * 512;   // [dir][B*S][512]
    float* Xl     = ws + o; o += (size_t)2 * 2048 * 128;   // [dir][B*S][128]
    float* Wg     = ws + o; o += (size_t)2 * 1024 * 384;   // [dir][B*N][384]
    float* feats  = ws + o; o += (size_t)2048 * 256;       // [B*S][2H]
    float* hist_h = ws + o; o += (size_t)32 * 129 * 128;
    float* hist_c = ws + o; o += (size_t)32 * 129 * 128;
    float* logits = ws + o; o += (size_t)2048 * 32;
    float* partb  = ws + o; o += 16;                        // ~19.3 MB total

    // setup GEMMs (r-direction Xg/Xl are time-reversed; Wg is NOT reversed)
    emb_gemm_kernel<<<128, 512, 0, stream>>>(char_emb, char_ids, f_Wcx, f_bc, Xg,                     128, 512, 2048, 128, 0);
    emb_gemm_kernel<<<128, 512, 0, stream>>>(char_emb, char_ids, r_Wcx, r_bc, Xg + (size_t)2048*512,  128, 512, 2048, 128, 1);
    emb_gemm_kernel<<<128, 128, 0, stream>>>(char_emb, char_ids, f_Wlx, f_bl, Xl,                     128, 128, 2048, 128, 0);
    emb_gemm_kernel<<<128, 128, 0, stream>>>(char_emb, char_ids, r_Wlx, r_bl, Xl + (size_t)2048*128,  128, 128, 2048, 128, 1);
    emb_gemm_kernel<<< 64, 384, 0, stream>>>(kb_emb, kb_word_ids, f_Wwx, f_bw, Wg,                    128, 384, 1024,  64, 0);
    emb_gemm_kernel<<< 64, 384, 0, stream>>>(kb_emb, kb_word_ids, r_Wwx, r_bw, Wg + (size_t)1024*384, 128, 384, 1024,  64, 0);

    lattice_kernel<<<32, 512, 0, stream>>>(Xg, Xl, Wg,
                                           f_Wch, r_Wch, f_Wwh, r_Wwh, f_Wlc, r_Wlc,
                                           word_begin, word_len, seqlen,
                                           hist_h, hist_c, feats);

    emb_gemm_kernel<<<128, 32, 0, stream>>>(feats, nullptr, dense_W, dense_b, logits, 256, 32, 2048, 128, 0);
    crf_kernel<<<16, 64, 0, stream>>>(logits, label, seqlen, crf_T, partb);
    finalize_kernel<<<1, 64, 0, stream>>>(partb, (float*)d_out);
}

// Round 2
// 811.294 us; speedup vs baseline: 1.6291x; 1.6291x over previous
//
#include <hip/hip_runtime.h>

// ---------------------------------------------------------------------------
// BiLstmCrf: bidirectional lattice-LSTM + CRF NLL, reduced to one scalar.
//
//   1. emb_gemm_kernel x6 : Xg = X@Wcx+bc (per dir, reversed for r),
//                           Xl = X@Wlx+bl, Wg = Xw@Wwx+bw
//   2. lattice_kernel     : 32 WGs (one per (batch,dir)), 512 thr.
//                           All recurrent weights resident in VGPRs as f16x2,
//                           matvecs via v_dot2_f32_f16. h history f16 /
//                           c history f32 in global ws. 2 barriers/step +
//                           2/word-event (software-pipelined).
//   3. emb_gemm_kernel    : logits = feats @ dense_W + dense_b
//   4. crf_kernel         : per-batch alpha recursion + gold score
//   5. finalize_kernel    : mean over batches -> d_out[0]
// ---------------------------------------------------------------------------

typedef _Float16 f16x2 __attribute__((ext_vector_type(2)));

__device__ __forceinline__ float sigm(float x) { return 1.f / (1.f + __expf(-x)); }
__device__ __forceinline__ float tanh_fast(float x) {
    return 1.f - 2.f / (__expf(2.f * x) + 1.f);   // exact at +-inf, ~1e-6 err
}

#if defined(__has_builtin)
#if __has_builtin(__builtin_amdgcn_fdot2)
#define FDOT2(a, b, c) __builtin_amdgcn_fdot2((a), (b), (c), false)
#endif
#endif
#ifndef FDOT2
__device__ __forceinline__ float fdot2_sw(f16x2 a, f16x2 b, float c) {
    return fmaf((float)a.x, (float)b.x, fmaf((float)a.y, (float)b.y, c));
}
#define FDOT2(a, b, c) fdot2_sw((a), (b), (c))
#endif

// out[row][j] = sum_k emb[idx(row)][k] * W[k][j] + bias[j]; K = 1<<kshift.
__global__ void emb_gemm_kernel(const float* __restrict__ emb,
                                const int* __restrict__ idx,
                                const float* __restrict__ W,
                                const float* __restrict__ bias,
                                float* __restrict__ out,
                                int kshift, int J, int rowsTotal, int Sdim, int rev)
{
    const int K = 1 << kshift;
    __shared__ __align__(16) float xs[16 * 256];
    __shared__ const float* srcs[16];
    const int r0 = blockIdx.x * 16;
    if (threadIdx.x < 16) {
        const int row = r0 + threadIdx.x;
        const float* s = nullptr;
        if (row < rowsTotal) {
            if (idx) {
                const int bb = row / Sdim;
                const int tt = row - bb * Sdim;
                const int tsrc = rev ? (Sdim - 1 - tt) : tt;
                s = emb + (size_t)idx[bb * Sdim + tsrc] * K;
            } else {
                s = emb + (size_t)row * K;
            }
        }
        srcs[threadIdx.x] = s;
    }
    __syncthreads();
    for (int i = threadIdx.x; i < 16 * K; i += blockDim.x) {
        const int rr = i >> kshift, k = i & (K - 1);
        const float* s = srcs[rr];
        xs[rr * K + k] = s ? s[k] : 0.f;
    }
    __syncthreads();
    const int j = threadIdx.x;   // blockDim.x == J
    float acc[16];
#pragma unroll
    for (int rr = 0; rr < 16; rr++) acc[rr] = 0.f;
    for (int k = 0; k < K; k++) {
        const float w = W[(size_t)k * J + j];
#pragma unroll
        for (int rr = 0; rr < 16; rr++) acc[rr] = fmaf(xs[rr * K + k], w, acc[rr]);
    }
    const float bj = bias[j];
    for (int rr = 0; rr < 16; rr++) {
        const int row = r0 + rr;
        if (row < rowsTotal) out[(size_t)row * J + j] = acc[rr] + bj;
    }
}

// One WG per (batch, dir). tid = kc*128 + jj: kc = k-chunk (32 ks), jj = col.
__global__ __launch_bounds__(512, 1)
void lattice_kernel(const float* __restrict__ Xg,    // [2][B*S][512]
                    const float* __restrict__ Xl,    // [2][B*S][128]
                    const float* __restrict__ Wgp,   // [2][B*N][384]
                    const float* __restrict__ Wch_f, const float* __restrict__ Wch_r,
                    const float* __restrict__ Wwh_f, const float* __restrict__ Wwh_r,
                    const float* __restrict__ Wlc_f, const float* __restrict__ Wlc_r,
                    const int* __restrict__ word_begin, const int* __restrict__ word_len,
                    const int* __restrict__ seqlen,
                    _Float16* __restrict__ hist_h,   // [32][129][128] f16
                    float* __restrict__ hist_c,      // [32][129][128] f32
                    float* __restrict__ feats)       // [B*S][256]
{
    const int bdid = blockIdx.x;           // 0..31
    const int b = bdid >> 1, dir = bdid & 1;
    const int tid = threadIdx.x;
    const int kc = tid >> 7;
    const int jj = tid & 127;

    const float* Wch = dir ? Wch_r : Wch_f;
    const float* Wwh = dir ? Wwh_r : Wwh_f;
    const float* Wlc = dir ? Wlc_r : Wlc_f;

    // ---- weights into VGPRs as packed f16 pairs (k-major pairs) -----------
    f16x2 wch2[64];    // [g][u2] : Wch[(kc*32+2u2(+1))*512 + g*128 + jj]
    {
        const float* base = Wch + (size_t)(kc * 32) * 512 + jj;
#pragma unroll
        for (int g = 0; g < 4; ++g)
#pragma unroll
            for (int u2 = 0; u2 < 16; ++u2) {
                f16x2 v;
                v.x = (_Float16)base[(size_t)(2 * u2) * 512 + g * 128];
                v.y = (_Float16)base[(size_t)(2 * u2 + 1) * 512 + g * 128];
                wch2[g * 16 + u2] = v;
            }
    }
    f16x2 wwh2[48];    // [g][u2] over 384-stride
    {
        const float* base = Wwh + (size_t)(kc * 32) * 384 + jj;
#pragma unroll
        for (int g = 0; g < 3; ++g)
#pragma unroll
            for (int u2 = 0; u2 < 16; ++u2) {
                f16x2 v;
                v.x = (_Float16)base[(size_t)(2 * u2) * 384 + g * 128];
                v.y = (_Float16)base[(size_t)(2 * u2 + 1) * 384 + g * 128];
                wwh2[g * 16 + u2] = v;
            }
    }
    f16x2 wlc2[16];
    {
        const float* base = Wlc + (size_t)(kc * 32) * 128 + jj;
#pragma unroll
        for (int u2 = 0; u2 < 16; ++u2) {
            f16x2 v;
            v.x = (_Float16)base[(size_t)(2 * u2) * 128];
            v.y = (_Float16)base[(size_t)(2 * u2 + 1) * 128];
            wlc2[u2] = v;
        }
    }

    // ---- LDS (static, ~18.5 KB) -------------------------------------------
    __shared__ __align__(16) float part[2048];    // char-gate partials [kc][g][jj]
    __shared__ __align__(16) float wpart[1536];   // word-gate partials [kc][g][jj]
    __shared__ __align__(16) float lpart[512];    // Wlc partials       [kc][jj]
    __shared__ __align__(16) f16x2 cw2s[64];      // cw as f16 pairs
    __shared__ int ev_start[129];
    __shared__ int cnts[128];
    __shared__ int fills[128];
    __shared__ short ev_word[64];
    __shared__ short wbeg_s[64];

    const int sl = seqlen[b];

    // ---- per-t word-event schedule ----------------------------------------
    if (tid < 128) { cnts[tid] = 0; fills[tid] = 0; }
    __syncthreads();
    int myvalid = 0, myed = 0;
    if (tid < 64) {
        const int bg = word_begin[b * 64 + tid];
        const int ln = word_len[b * 64 + tid];
        int ef = bg + ln; if (ef > 127) ef = 127;   // end = min(begin+len, S-1)
        myvalid = (ef < sl);                        // word_valid
        const int bd_ = dir ? (127 - ef) : bg;
        const int ed_ = dir ? (127 - bg) : ef;
        wbeg_s[tid] = (short)bd_;
        myed = ed_;
        if (myvalid) atomicAdd(&cnts[ed_], 1);
    }
    __syncthreads();
    if (tid == 0) {
        int run = 0;
        ev_start[0] = 0;
        for (int t = 0; t < 128; ++t) { run += cnts[t]; ev_start[t + 1] = run; }
    }
    __syncthreads();
    if (tid < 64 && myvalid) {
        const int pos = atomicAdd(&fills[myed], 1);
        ev_word[ev_start[myed] + pos] = (short)tid;
    }
    _Float16* hh = hist_h + (size_t)bdid * 129 * 128;
    float*    ch = hist_c + (size_t)bdid * 129 * 128;
    if (tid < 128) { hh[tid] = (_Float16)0.f; ch[tid] = 0.f; }   // slot 0
    __syncthreads();

    const float* Xg_b = Xg + ((size_t)dir * 2048 + (size_t)b * 128) * 512;
    const float* Xl_b = Xl + ((size_t)dir * 2048 + (size_t)b * 128) * 128;
    const float* Wg_b = Wgp + ((size_t)dir * 1024 + (size_t)b * 64) * 384;

    float h_reg = 0.f, c_reg = 0.f;   // owner-thread (tid<128) state

    // ---- main scan --------------------------------------------------------
    for (int t = 0; t < 128; ++t) {
        const int e0 = ev_start[t];
        const int E  = ev_start[t + 1] - e0;

        // prefetches (loads in flight across the matvec, drained at barrier A)
        const float xg = Xg_b[(size_t)t * 512 + tid];
        float xl = 0.f, wg0 = 0.f, wg1 = 0.f, wg2 = 0.f, cb = 0.f;
        int bg0 = 0;
        if (E > 0) {
            const int w0 = ev_word[e0];
            bg0 = wbeg_s[w0];
            if (tid < 128) {
                xl = Xl_b[(size_t)t * 128 + tid];
                const float* wgr = Wg_b + (size_t)w0 * 384;
                wg0 = wgr[tid]; wg1 = wgr[128 + tid]; wg2 = wgr[256 + tid];
                cb = ch[(size_t)bg0 * 128 + tid];
            }
        }

        // P1: char matvec (+ first event's Wwh matvec)
        {
            const f16x2* hrow = (const f16x2*)(hh + (size_t)t * 128) + kc * 16;
            f16x2 hv[16];
#pragma unroll
            for (int u2 = 0; u2 < 16; ++u2) hv[u2] = hrow[u2];
            float p0 = 0.f, p1 = 0.f, p2 = 0.f, p3 = 0.f;
#pragma unroll
            for (int u2 = 0; u2 < 16; ++u2) {
                p0 = FDOT2(wch2[u2],      hv[u2], p0);
                p1 = FDOT2(wch2[16 + u2], hv[u2], p1);
                p2 = FDOT2(wch2[32 + u2], hv[u2], p2);
                p3 = FDOT2(wch2[48 + u2], hv[u2], p3);
            }
            if      (kc == 0) p0 += xg;
            else if (kc == 1) p1 += xg;
            else if (kc == 2) p2 += xg;
            else              p3 += xg;
            part[kc * 512 +       jj] = p0;
            part[kc * 512 + 128 + jj] = p1;
            part[kc * 512 + 256 + jj] = p2;
            part[kc * 512 + 384 + jj] = p3;
            if (E > 0) {
                const f16x2* hbrow = (const f16x2*)(hh + (size_t)bg0 * 128) + kc * 16;
                float q0 = 0.f, q1 = 0.f, q2 = 0.f;
#pragma unroll
                for (int u2 = 0; u2 < 16; ++u2) {
                    const f16x2 hb = hbrow[u2];
                    q0 = FDOT2(wwh2[u2],      hb, q0);
                    q1 = FDOT2(wwh2[16 + u2], hb, q1);
                    q2 = FDOT2(wwh2[32 + u2], hb, q2);
                }
                wpart[kc * 384 +       jj] = q0;
                wpart[kc * 384 + 128 + jj] = q1;
                wpart[kc * 384 + 256 + jj] = q2;
            }
        }
        __syncthreads();   // A

        // P2 (owner threads): gate sums + activations; first event's cw
        float gi = 0.f, gf = 0.f, go = 0.f, gg = 0.f, cw_cur = 0.f;
        if (tid < 128) {
            const float a0 = part[tid]       + part[512 + tid]  + part[1024 + tid] + part[1536 + tid];
            const float a1 = part[128 + tid] + part[640 + tid]  + part[1152 + tid] + part[1664 + tid];
            const float a2 = part[256 + tid] + part[768 + tid]  + part[1280 + tid] + part[1792 + tid];
            const float a3 = part[384 + tid] + part[896 + tid]  + part[1408 + tid] + part[1920 + tid];
            gi = sigm(a0); gf = sigm(a1); go = sigm(a2); gg = tanh_fast(a3);
            if (E > 0) {
                const float wi = wg0 + wpart[tid]       + wpart[384 + tid] + wpart[768 + tid]  + wpart[1152 + tid];
                const float wf = wg1 + wpart[128 + tid] + wpart[512 + tid] + wpart[896 + tid]  + wpart[1280 + tid];
                const float wv = wg2 + wpart[256 + tid] + wpart[640 + tid] + wpart[1024 + tid] + wpart[1408 + tid];
                cw_cur = sigm(wf) * cb + sigm(wi) * tanh_fast(wv);
                ((_Float16*)cw2s)[tid] = (_Float16)cw_cur;
            }
        }

        // event loop, software-pipelined: 2 barriers per event
        float accn = 0.f, accd = 0.f;
        for (int e = 0; e < E; ++e) {
            __syncthreads();               // cw2s(e) ready
            const bool more = (e + 1 < E);
            int bgn = 0; float cbn = 0.f, wn0 = 0.f, wn1 = 0.f, wn2 = 0.f;
            if (more) {
                const int wn = ev_word[e0 + e + 1];
                bgn = wbeg_s[wn];
                if (tid < 128) {
                    const float* wgr = Wg_b + (size_t)wn * 384;
                    wn0 = wgr[tid]; wn1 = wgr[128 + tid]; wn2 = wgr[256 + tid];
                    cbn = ch[(size_t)bgn * 128 + tid];
                }
            }
            {   // cw(e) @ Wlc
                float r = 0.f;
#pragma unroll
                for (int u2 = 0; u2 < 16; ++u2) r = FDOT2(wlc2[u2], cw2s[kc * 16 + u2], r);
                lpart[kc * 128 + jj] = r;
            }
            if (more) {   // next event's hb @ Wwh
                const f16x2* hbrow = (const f16x2*)(hh + (size_t)bgn * 128) + kc * 16;
                float q0 = 0.f, q1 = 0.f, q2 = 0.f;
#pragma unroll
                for (int u2 = 0; u2 < 16; ++u2) {
                    const f16x2 hb = hbrow[u2];
                    q0 = FDOT2(wwh2[u2],      hb, q0);
                    q1 = FDOT2(wwh2[16 + u2], hb, q1);
                    q2 = FDOT2(wwh2[32 + u2], hb, q2);
                }
                wpart[kc * 384 +       jj] = q0;
                wpart[kc * 384 + 128 + jj] = q1;
                wpart[kc * 384 + 256 + jj] = q2;
            }
            __syncthreads();               // lpart(e) (+ wpart(e+1)) ready
            if (tid < 128) {
                const float lg = sigm(xl + lpart[tid] + lpart[128 + tid] + lpart[256 + tid] + lpart[384 + tid]);
                const float ew = __expf(lg);
                accn = fmaf(ew, cw_cur, accn);
                accd += ew;
                if (more) {
                    const float wi = wn0 + wpart[tid]       + wpart[384 + tid] + wpart[768 + tid]  + wpart[1152 + tid];
                    const float wf = wn1 + wpart[128 + tid] + wpart[512 + tid] + wpart[896 + tid]  + wpart[1280 + tid];
                    const float wv = wn2 + wpart[256 + tid] + wpart[640 + tid] + wpart[1024 + tid] + wpart[1408 + tid];
                    cw_cur = sigm(wf) * cbn + sigm(wi) * tanh_fast(wv);
                    ((_Float16*)cw2s)[tid] = (_Float16)cw_cur;
                }
            }
        }

        // ---- c/h update ----------------------------------------------------
        if (tid < 128) {
            float c_t;
            if (E > 0) {
                const float ec = __expf(gi);
                c_t = (ec * gg + accn) / (ec + accd);
            } else {
                c_t = gf * c_reg + gi * gg;
            }
            const float h_t = go * tanh_fast(c_t);
            const bool v = dir ? (t >= 128 - sl) : (t < sl);
            const float hn = v ? h_t : h_reg;
            const float cn = v ? c_t : c_reg;
            h_reg = hn; c_reg = cn;
            hh[(size_t)(t + 1) * 128 + tid] = (_Float16)hn;
            ch[(size_t)(t + 1) * 128 + tid] = cn;
        }
        __syncthreads();   // B
    }

    // ---- epilogue: feats from h history (masked, un-reversed) -------------
    for (int i = tid; i < 128 * 128; i += 512) {
        const int t = i >> 7, j = i & 127;
        const bool v = dir ? (t >= 128 - sl) : (t < sl);
        const float hv = v ? (float)hh[(size_t)(t + 1) * 128 + j] : 0.f;
        const int s = dir ? (127 - t) : t;
        feats[((size_t)b * 128 + s) * 256 + dir * 128 + j] = hv;
    }
}

// One WG (64 thr) per batch: gold score + alpha recursion + logZ.
__global__ void crf_kernel(const float* __restrict__ logits,  // [B*S][32]
                           const int* __restrict__ label,     // [B*S]
                           const int* __restrict__ seqlen,
                           const float* __restrict__ T,       // [32][32]
                           float* __restrict__ out_part)      // [B]
{
    const int b = blockIdx.x;
    const int tid = threadIdx.x;   // 64
    __shared__ float Tl[1024];
    __shared__ float alpha[32];
    __shared__ float red[64];
    for (int i = tid; i < 1024; i += 64) Tl[i] = T[i];
    const float* lg = logits + (size_t)b * 128 * 32;
    const int* lab = label + b * 128;
    const int sl = seqlen[b];

    float g = 0.f;
    for (int t = tid; t < 128; t += 64) {
        if (t < sl) {
            g += lg[t * 32 + lab[t]];
            if (t >= 1) g += T[lab[t - 1] * 32 + lab[t]];
        }
    }
    red[tid] = g;
    __syncthreads();
    for (int s2 = 32; s2 > 0; s2 >>= 1) {
        if (tid < s2) red[tid] += red[tid + s2];
        __syncthreads();
    }
    if (tid < 32) alpha[tid] = lg[tid];
    __syncthreads();
    for (int t = 1; t < 128; t++) {
        float nv = 0.f;
        if (tid < 32) {
            float m = -1e30f;
#pragma unroll
            for (int i = 0; i < 32; i++) m = fmaxf(m, alpha[i] + Tl[i * 32 + tid]);
            float s = 0.f;
#pragma unroll
            for (int i = 0; i < 32; i++) s += __expf(alpha[i] + Tl[i * 32 + tid] - m);
            nv = m + __logf(s) + lg[t * 32 + tid];
            if (t >= sl) nv = alpha[tid];
        }
        __syncthreads();
        if (tid < 32) alpha[tid] = nv;
        __syncthreads();
    }
    if (tid == 0) {
        float m = -1e30f;
        for (int i = 0; i < 32; i++) m = fmaxf(m, alpha[i]);
        float s = 0.f;
        for (int i = 0; i < 32; i++) s += __expf(alpha[i] - m);
        out_part[b] = (m + __logf(s)) - red[0];
    }
}

__global__ void finalize_kernel(const float* __restrict__ partb, float* __restrict__ out)
{
    if (threadIdx.x == 0 && blockIdx.x == 0) {
        float s = 0.f;
        for (int i = 0; i < 16; i++) s += partb[i];
        out[0] = s * (1.f / 16.f);
    }
}

extern "C" void kernel_launch(void* const* d_in, const int* in_sizes, int n_in,
                              void* d_out, int out_size, void* d_ws, size_t ws_size,
                              hipStream_t stream)
{
    (void)in_sizes; (void)n_in; (void)out_size; (void)ws_size;
    const int*   char_ids    = (const int*)d_in[0];
    const int*   kb_word_ids = (const int*)d_in[1];
    const int*   word_begin  = (const int*)d_in[2];
    const int*   word_len    = (const int*)d_in[3];
    const int*   label       = (const int*)d_in[4];
    const int*   seqlen      = (const int*)d_in[5];
    const float* char_emb    = (const float*)d_in[6];
    const float* kb_emb      = (const float*)d_in[7];
    const float* dense_W     = (const float*)d_in[8];
    const float* dense_b     = (const float*)d_in[9];
    const float* crf_T       = (const float*)d_in[10];
    const float* f_Wcx = (const float*)d_in[11];
    const float* f_Wch = (const float*)d_in[12];
    const float* f_bc  = (const float*)d_in[13];
    const float* f_Wwx = (const float*)d_in[14];
    const float* f_Wwh = (const float*)d_in[15];
    const float* f_bw  = (const float*)d_in[16];
    const float* f_Wlx = (const float*)d_in[17];
    const float* f_Wlc = (const float*)d_in[18];
    const float* f_bl  = (const float*)d_in[19];
    const float* r_Wcx = (const float*)d_in[20];
    const float* r_Wch = (const float*)d_in[21];
    const float* r_bc  = (const float*)d_in[22];
    const float* r_Wwx = (const float*)d_in[23];
    const float* r_Wwh = (const float*)d_in[24];
    const float* r_bw  = (const float*)d_in[25];
    const float* r_Wlx = (const float*)d_in[26];
    const float* r_Wlc = (const float*)d_in[27];
    const float* r_bl  = (const float*)d_in[28];

    float* ws = (float*)d_ws;
    size_t o = 0;
    float* Xg     = ws + o; o += (size_t)2 * 2048 * 512;   // [dir][B*S][512]
    float* Xl     = ws + o; o += (size_t)2 * 2048 * 128;   // [dir][B*S][128]
    float* Wg     = ws + o; o += (size_t)2 * 1024 * 384;   // [dir][B*N][384]
    float* feats  = ws + o; o += (size_t)2048 * 256;       // [B*S][2H]
    _Float16* hh16 = (_Float16*)(ws + o); o += (size_t)32 * 129 * 128 / 2;  // f16 h-history
    float* chist  = ws + o; o += (size_t)32 * 129 * 128;   // f32 c-history
    float* logits = ws + o; o += (size_t)2048 * 32;
    float* partb  = ws + o; o += 16;                       // ~18 MB total

    // setup GEMMs (r-direction Xg/Xl time-reversed; Wg NOT reversed)
    emb_gemm_kernel<<<128, 512, 0, stream>>>(char_emb, char_ids, f_Wcx, f_bc, Xg,                     7, 512, 2048, 128, 0);
    emb_gemm_kernel<<<128, 512, 0, stream>>>(char_emb, char_ids, r_Wcx, r_bc, Xg + (size_t)2048*512,  7, 512, 2048, 128, 1);
    emb_gemm_kernel<<<128, 128, 0, stream>>>(char_emb, char_ids, f_Wlx, f_bl, Xl,                     7, 128, 2048, 128, 0);
    emb_gemm_kernel<<<128, 128, 0, stream>>>(char_emb, char_ids, r_Wlx, r_bl, Xl + (size_t)2048*128,  7, 128, 2048, 128, 1);
    emb_gemm_kernel<<< 64, 384, 0, stream>>>(kb_emb, kb_word_ids, f_Wwx, f_bw, Wg,                    7, 384, 1024,  64, 0);
    emb_gemm_kernel<<< 64, 384, 0, stream>>>(kb_emb, kb_word_ids, r_Wwx, r_bw, Wg + (size_t)1024*384, 7, 384, 1024,  64, 0);

    lattice_kernel<<<32, 512, 0, stream>>>(Xg, Xl, Wg,
                                           f_Wch, r_Wch, f_Wwh, r_Wwh, f_Wlc, r_Wlc,
                                           word_begin, word_len, seqlen,
                                           hh16, chist, feats);

    emb_gemm_kernel<<<128, 32, 0, stream>>>(feats, nullptr, dense_W, dense_b, logits, 8, 32, 2048, 128, 0);
    crf_kernel<<<16, 64, 0, stream>>>(logits, label, seqlen, crf_T, partb);
    finalize_kernel<<<1, 64, 0, stream>>>(partb, (float*)d_out);
}

// Round 3
// 540.611 us; speedup vs baseline: 2.4447x; 1.5007x over previous
//
#include <hip/hip_runtime.h>

// ---------------------------------------------------------------------------
// BiLstmCrf: bidirectional lattice-LSTM + CRF NLL -> one scalar.
//
//   1. gemm_pair x3 : Xg(f+r), Xl(f+r), Wg(f+r)  (y-dim of grid = direction)
//   2. lattice_kernel : 32 WGs (one per (batch,dir)), 512 thr.
//        h history (f16) + c history (f32) resident in LDS (no global
//        round-trip on the recurrent path). Weights in VGPRs (f16x2, dot2).
//        Barriers are lgkm-only (inline asm) so global prefetches stay in
//        flight. Word events processed in parallel (chunks of 2).
//   3. gemm_pair : logits = feats @ dense_W + dense_b
//   4. crf_kernel : 2 batches per wave, T columns in registers
//   5. finalize_kernel
// ---------------------------------------------------------------------------

typedef _Float16 f16x2 __attribute__((ext_vector_type(2)));

__device__ __forceinline__ float sigm(float x) { return 1.f / (1.f + __expf(-x)); }
__device__ __forceinline__ float tanh_fast(float x) {
    return 1.f - 2.f / (__expf(2.f * x) + 1.f);
}
// lgkm-only barrier: LDS ops drained, vmem loads stay outstanding.
__device__ __forceinline__ void bar_lgkm() {
    asm volatile("s_waitcnt lgkmcnt(0)\n\ts_barrier" ::: "memory");
}

#if defined(__has_builtin)
#if __has_builtin(__builtin_amdgcn_fdot2)
#define FDOT2(a, b, c) __builtin_amdgcn_fdot2((a), (b), (c), false)
#endif
#endif
#ifndef FDOT2
__device__ __forceinline__ float fdot2_sw(f16x2 a, f16x2 b, float c) {
    return fmaf((float)a.x, (float)b.x, fmaf((float)a.y, (float)b.y, c));
}
#define FDOT2(a, b, c) fdot2_sw((a), (b), (c))
#endif

// ---------------------------------------------------------------------------
// out[y][row][j] = sum_k emb[idx_y(row)][k] * W_y[k][j] + b_y[j]
// blockIdx.y selects (W,bias,rev). float4 everywhere.
// ---------------------------------------------------------------------------
template <int K, int J, int RPB, int BLK>
__global__ __launch_bounds__(BLK)
void gemm_pair(const float* __restrict__ emb, const int* __restrict__ idx,
               const float* __restrict__ W0, const float* __restrict__ W1,
               const float* __restrict__ b0, const float* __restrict__ b1,
               float* __restrict__ out, int rowsTotal, int Sdim, int revmode)
{
    constexpr int NJ4 = J / 4;
    constexpr int RT  = BLK / NJ4;
    constexpr int RPT = RPB / RT;
    static_assert(BLK % NJ4 == 0 && RPB % RT == 0, "layout");
    const int y = blockIdx.y;
    const float* __restrict__ W    = y ? W1 : W0;
    const float* __restrict__ bias = y ? b1 : b0;
    float* __restrict__ outp = out + (size_t)y * rowsTotal * J;
    const int rev = (revmode && y) ? 1 : 0;

    __shared__ __align__(16) float xs[RPB * K];
    __shared__ const float* srcs[RPB];
    const int tid = threadIdx.x;
    const int r0 = blockIdx.x * RPB;
    if (tid < RPB) {
        const int row = r0 + tid;
        const float* s = nullptr;
        if (row < rowsTotal) {
            if (idx) {
                const int bb = row / Sdim, tt = row - bb * Sdim;
                const int ts = rev ? (Sdim - 1 - tt) : tt;
                s = emb + (size_t)idx[bb * Sdim + ts] * K;
            } else {
                s = emb + (size_t)row * K;
            }
        }
        srcs[tid] = s;
    }
    __syncthreads();
    constexpr int NQ = RPB * K / 4;
    for (int q = tid; q < NQ; q += BLK) {
        const int rr = q / (K / 4), qq = q - rr * (K / 4);
        const float4* s = (const float4*)srcs[rr];
        ((float4*)xs)[q] = s ? s[qq] : make_float4(0.f, 0.f, 0.f, 0.f);
    }
    __syncthreads();

    const int jq = tid % NJ4;
    const int rg = tid / NJ4;
    float4 acc[RPT];
#pragma unroll
    for (int r = 0; r < RPT; ++r) acc[r] = make_float4(0.f, 0.f, 0.f, 0.f);
    const float4* __restrict__ W4 = (const float4*)W;
#pragma unroll 4
    for (int k = 0; k < K; ++k) {
        const float4 wv = W4[(size_t)k * NJ4 + jq];
#pragma unroll
        for (int r = 0; r < RPT; ++r) {
            const float xv = xs[(rg * RPT + r) * K + k];
            acc[r].x = fmaf(xv, wv.x, acc[r].x);
            acc[r].y = fmaf(xv, wv.y, acc[r].y);
            acc[r].z = fmaf(xv, wv.z, acc[r].z);
            acc[r].w = fmaf(xv, wv.w, acc[r].w);
        }
    }
    const float4 bv = ((const float4*)bias)[jq];
#pragma unroll
    for (int r = 0; r < RPT; ++r) {
        const int row = r0 + rg * RPT + r;
        if (row < rowsTotal)
            ((float4*)outp)[(size_t)row * NJ4 + jq] =
                make_float4(acc[r].x + bv.x, acc[r].y + bv.y,
                            acc[r].z + bv.z, acc[r].w + bv.w);
    }
}

// ---------------------------------------------------------------------------
// Lattice scan. One WG per (batch,dir); tid = kc*128 + jj.
// Dynamic LDS: hh (f16, 129*128) + ch (f32, 129*128).
// ---------------------------------------------------------------------------
#define HH_BYTES (129 * 128 * 2)
#define CH_BYTES (129 * 128 * 4)
#define LAT_DYN_SMEM (HH_BYTES + CH_BYTES)

__global__ __launch_bounds__(512, 2)
void lattice_kernel(const float* __restrict__ Xg,    // [2][B*S][512]
                    const float* __restrict__ Xl,    // [2][B*S][128]
                    const float* __restrict__ Wgp,   // [2][B*N][384]
                    const float* __restrict__ Wch_f, const float* __restrict__ Wch_r,
                    const float* __restrict__ Wwh_f, const float* __restrict__ Wwh_r,
                    const float* __restrict__ Wlc_f, const float* __restrict__ Wlc_r,
                    const int* __restrict__ word_begin, const int* __restrict__ word_len,
                    const int* __restrict__ seqlen,
                    float* __restrict__ feats)       // [B*S][256]
{
    extern __shared__ __align__(16) char dyn_smem[];
    _Float16* hh = (_Float16*)dyn_smem;                    // [129][128]
    float*    ch = (float*)(dyn_smem + HH_BYTES);          // [129][128]

    const int bdid = blockIdx.x;
    const int b = bdid >> 1, dir = bdid & 1;
    const int tid = threadIdx.x;
    const int kc = tid >> 7;
    const int jj = tid & 127;

    const float* Wch = dir ? Wch_r : Wch_f;
    const float* Wwh = dir ? Wwh_r : Wwh_f;
    const float* Wlc = dir ? Wlc_r : Wlc_f;

    // ---- weights -> VGPRs as f16x2 ----------------------------------------
    f16x2 wch2[64];
    {
        const float* base = Wch + (size_t)(kc * 32) * 512 + jj;
#pragma unroll
        for (int g = 0; g < 4; ++g)
#pragma unroll
            for (int u2 = 0; u2 < 16; ++u2) {
                f16x2 v;
                v.x = (_Float16)base[(size_t)(2 * u2) * 512 + g * 128];
                v.y = (_Float16)base[(size_t)(2 * u2 + 1) * 512 + g * 128];
                wch2[g * 16 + u2] = v;
            }
    }
    f16x2 wwh2[48];
    {
        const float* base = Wwh + (size_t)(kc * 32) * 384 + jj;
#pragma unroll
        for (int g = 0; g < 3; ++g)
#pragma unroll
            for (int u2 = 0; u2 < 16; ++u2) {
                f16x2 v;
                v.x = (_Float16)base[(size_t)(2 * u2) * 384 + g * 128];
                v.y = (_Float16)base[(size_t)(2 * u2 + 1) * 384 + g * 128];
                wwh2[g * 16 + u2] = v;
            }
    }
    f16x2 wlc2[16];
    {
        const float* base = Wlc + (size_t)(kc * 32) * 128 + jj;
#pragma unroll
        for (int u2 = 0; u2 < 16; ++u2) {
            f16x2 v;
            v.x = (_Float16)base[(size_t)(2 * u2) * 128];
            v.y = (_Float16)base[(size_t)(2 * u2 + 1) * 128];
            wlc2[u2] = v;
        }
    }

    // ---- static LDS --------------------------------------------------------
    __shared__ __align__(16) float part[2048];      // [kc][g][jj]
    __shared__ __align__(16) float wpart[2 * 1536]; // [slot][kc][g][jj]
    __shared__ __align__(16) float lpart[2 * 512];  // [slot][kc][jj]
    __shared__ __align__(16) _Float16 cw2s[2 * 128];
    __shared__ int ev_start[129];
    __shared__ int cnts[128];
    __shared__ int fills[128];
    __shared__ short ev_word[64];
    __shared__ short wbeg_s[64];

    const int sl = seqlen[b];

    // ---- event schedule ----------------------------------------------------
    if (tid < 128) { cnts[tid] = 0; fills[tid] = 0; }
    __syncthreads();
    int myvalid = 0, myed = 0;
    if (tid < 64) {
        const int bg = word_begin[b * 64 + tid];
        const int ln = word_len[b * 64 + tid];
        int ef = bg + ln; if (ef > 127) ef = 127;
        myvalid = (ef < sl);
        const int bd_ = dir ? (127 - ef) : bg;
        const int ed_ = dir ? (127 - bg) : ef;
        wbeg_s[tid] = (short)bd_;
        myed = ed_;
        if (myvalid) atomicAdd(&cnts[ed_], 1);
    }
    __syncthreads();
    if (tid == 0) {
        int run = 0; ev_start[0] = 0;
        for (int t = 0; t < 128; ++t) { run += cnts[t]; ev_start[t + 1] = run; }
    }
    __syncthreads();
    if (tid < 64 && myvalid) {
        const int pos = atomicAdd(&fills[myed], 1);
        ev_word[ev_start[myed] + pos] = (short)tid;
    }
    if (tid < 128) { hh[tid] = (_Float16)0.f; ch[tid] = 0.f; }   // slot 0
    __syncthreads();

    const float* Xg_b = Xg + ((size_t)dir * 2048 + (size_t)b * 128) * 512;
    const float* Xl_b = Xl + ((size_t)dir * 2048 + (size_t)b * 128) * 128;
    const float* Wg_b = Wgp + ((size_t)dir * 1024 + (size_t)b * 64) * 384;

    float h_reg = 0.f, c_reg = 0.f;
    float xg_cur = Xg_b[tid];   // t=0 prefetch

    for (int t = 0; t < 128; ++t) {
        const int e0 = ev_start[t];
        const int E  = ev_start[t + 1] - e0;
        const int ec0 = E < 2 ? E : 2;

        // metadata + global prefetch (in flight across lgkm barriers)
        int bgs[2] = {0, 0};
        float wgp[2][3];
        float xl = 0.f;
#pragma unroll
        for (int s = 0; s < 2; ++s)
            if (s < ec0) {
                const int w = ev_word[e0 + s];
                bgs[s] = wbeg_s[w];
                if (tid < 128) {
                    const float* wgr = Wg_b + (size_t)w * 384;
                    wgp[s][0] = wgr[tid]; wgp[s][1] = wgr[128 + tid]; wgp[s][2] = wgr[256 + tid];
                }
            }
        if (E > 0 && tid < 128) xl = Xl_b[(size_t)t * 128 + tid];
        const float xg_nxt = (t < 127) ? Xg_b[(size_t)(t + 1) * 512 + tid] : 0.f;

        // ---- P1: char matvec + chunk-0 Wwh matvecs ------------------------
        {
            const f16x2* hrow = (const f16x2*)(hh + (size_t)t * 128) + kc * 16;
            f16x2 hv[16];
#pragma unroll
            for (int u2 = 0; u2 < 16; ++u2) hv[u2] = hrow[u2];
            float p0 = 0.f, p1 = 0.f, p2 = 0.f, p3 = 0.f;
#pragma unroll
            for (int u2 = 0; u2 < 16; ++u2) {
                p0 = FDOT2(wch2[u2],      hv[u2], p0);
                p1 = FDOT2(wch2[16 + u2], hv[u2], p1);
                p2 = FDOT2(wch2[32 + u2], hv[u2], p2);
                p3 = FDOT2(wch2[48 + u2], hv[u2], p3);
            }
            if      (kc == 0) p0 += xg_cur;
            else if (kc == 1) p1 += xg_cur;
            else if (kc == 2) p2 += xg_cur;
            else              p3 += xg_cur;
            part[kc * 512 +       jj] = p0;
            part[kc * 512 + 128 + jj] = p1;
            part[kc * 512 + 256 + jj] = p2;
            part[kc * 512 + 384 + jj] = p3;
        }
#pragma unroll
        for (int s = 0; s < 2; ++s)
            if (s < ec0) {
                const f16x2* hbrow = (const f16x2*)(hh + (size_t)bgs[s] * 128) + kc * 16;
                float q0 = 0.f, q1 = 0.f, q2 = 0.f;
#pragma unroll
                for (int u2 = 0; u2 < 16; ++u2) {
                    const f16x2 hb = hbrow[u2];
                    q0 = FDOT2(wwh2[u2],      hb, q0);
                    q1 = FDOT2(wwh2[16 + u2], hb, q1);
                    q2 = FDOT2(wwh2[32 + u2], hb, q2);
                }
                wpart[s * 1536 + kc * 384 +       jj] = q0;
                wpart[s * 1536 + kc * 384 + 128 + jj] = q1;
                wpart[s * 1536 + kc * 384 + 256 + jj] = q2;
            }
        bar_lgkm();   // A

        // ---- P2 (owners): gates + chunk-0 cw ------------------------------
        float gi = 0.f, gf = 0.f, go = 0.f, gg = 0.f;
        float cwreg[2] = {0.f, 0.f};
        if (tid < 128) {
            const float a0 = part[tid]       + part[512 + tid]  + part[1024 + tid] + part[1536 + tid];
            const float a1 = part[128 + tid] + part[640 + tid]  + part[1152 + tid] + part[1664 + tid];
            const float a2 = part[256 + tid] + part[768 + tid]  + part[1280 + tid] + part[1792 + tid];
            const float a3 = part[384 + tid] + part[896 + tid]  + part[1408 + tid] + part[1920 + tid];
            gi = sigm(a0); gf = sigm(a1); go = sigm(a2); gg = tanh_fast(a3);
#pragma unroll
            for (int s = 0; s < 2; ++s)
                if (s < ec0) {
                    const int sb = s * 1536;
                    const float cb = ch[(size_t)bgs[s] * 128 + tid];
                    const float wi = wgp[s][0] + wpart[sb + tid]       + wpart[sb + 384 + tid] + wpart[sb + 768 + tid]  + wpart[sb + 1152 + tid];
                    const float wf = wgp[s][1] + wpart[sb + 128 + tid] + wpart[sb + 512 + tid] + wpart[sb + 896 + tid]  + wpart[sb + 1280 + tid];
                    const float wv = wgp[s][2] + wpart[sb + 256 + tid] + wpart[sb + 640 + tid] + wpart[sb + 1024 + tid] + wpart[sb + 1408 + tid];
                    const float cwv = sigm(wf) * cb + sigm(wi) * tanh_fast(wv);
                    cwreg[s] = cwv;
                    cw2s[s * 128 + tid] = (_Float16)cwv;
                }
        }

        float accn = 0.f, accd = 0.f;
        if (E > 0) {
            bar_lgkm();
            const int nc = (E + 1) >> 1;
            for (int c = 0; c < nc; ++c) {
                const int base = c * 2;
                const int en = (E - base) < 2 ? (E - base) : 2;
                // P3: Wlc matvecs for this chunk
#pragma unroll
                for (int s = 0; s < 2; ++s)
                    if (s < en) {
                        const f16x2* cwrow = (const f16x2*)(cw2s + s * 128) + kc * 16;
                        float r = 0.f;
#pragma unroll
                        for (int u2 = 0; u2 < 16; ++u2) r = FDOT2(wlc2[u2], cwrow[u2], r);
                        lpart[s * 512 + kc * 128 + jj] = r;
                    }
                // prep next chunk: metadata + Wwh matvecs
                const int nb = base + 2;
                int nn = E - nb; nn = nn < 0 ? 0 : (nn > 2 ? 2 : nn);
                int bgs2[2] = {0, 0};
                float wgp2[2][3];
#pragma unroll
                for (int s = 0; s < 2; ++s)
                    if (s < nn) {
                        const int w = ev_word[e0 + nb + s];
                        bgs2[s] = wbeg_s[w];
                        if (tid < 128) {
                            const float* wgr = Wg_b + (size_t)w * 384;
                            wgp2[s][0] = wgr[tid]; wgp2[s][1] = wgr[128 + tid]; wgp2[s][2] = wgr[256 + tid];
                        }
                    }
#pragma unroll
                for (int s = 0; s < 2; ++s)
                    if (s < nn) {
                        const f16x2* hbrow = (const f16x2*)(hh + (size_t)bgs2[s] * 128) + kc * 16;
                        float q0 = 0.f, q1 = 0.f, q2 = 0.f;
#pragma unroll
                        for (int u2 = 0; u2 < 16; ++u2) {
                            const f16x2 hb = hbrow[u2];
                            q0 = FDOT2(wwh2[u2],      hb, q0);
                            q1 = FDOT2(wwh2[16 + u2], hb, q1);
                            q2 = FDOT2(wwh2[32 + u2], hb, q2);
                        }
                        wpart[s * 1536 + kc * 384 +       jj] = q0;
                        wpart[s * 1536 + kc * 384 + 128 + jj] = q1;
                        wpart[s * 1536 + kc * 384 + 256 + jj] = q2;
                    }
                bar_lgkm();
                // P4 (owners): accumulate this chunk; cw for next chunk
                if (tid < 128) {
#pragma unroll
                    for (int s = 0; s < 2; ++s)
                        if (s < en) {
                            const float lg = sigm(xl + lpart[s * 512 + tid] + lpart[s * 512 + 128 + tid]
                                                     + lpart[s * 512 + 256 + tid] + lpart[s * 512 + 384 + tid]);
                            const float ew = __expf(lg);
                            accn = fmaf(ew, cwreg[s], accn);
                            accd += ew;
                        }
#pragma unroll
                    for (int s = 0; s < 2; ++s)
                        if (s < nn) {
                            const int sb = s * 1536;
                            const float cb = ch[(size_t)bgs2[s] * 128 + tid];
                            const float wi = wgp2[s][0] + wpart[sb + tid]       + wpart[sb + 384 + tid] + wpart[sb + 768 + tid]  + wpart[sb + 1152 + tid];
                            const float wf = wgp2[s][1] + wpart[sb + 128 + tid] + wpart[sb + 512 + tid] + wpart[sb + 896 + tid]  + wpart[sb + 1280 + tid];
                            const float wv = wgp2[s][2] + wpart[sb + 256 + tid] + wpart[sb + 640 + tid] + wpart[sb + 1024 + tid] + wpart[sb + 1408 + tid];
                            const float cwv = sigm(wf) * cb + sigm(wi) * tanh_fast(wv);
                            cwreg[s] = cwv;
                            cw2s[s * 128 + tid] = (_Float16)cwv;
                        }
                }
                if (c + 1 < nc) bar_lgkm();
            }
        }

        // ---- update --------------------------------------------------------
        if (tid < 128) {
            float c_t;
            if (E > 0) {
                const float ec = __expf(gi);
                c_t = (ec * gg + accn) / (ec + accd);
            } else {
                c_t = gf * c_reg + gi * gg;
            }
            const float h_t = go * tanh_fast(c_t);
            const bool v = dir ? (t >= 128 - sl) : (t < sl);
            const float hn = v ? h_t : h_reg;
            const float cn = v ? c_t : c_reg;
            h_reg = hn; c_reg = cn;
            hh[(size_t)(t + 1) * 128 + tid] = (_Float16)hn;
            ch[(size_t)(t + 1) * 128 + tid] = cn;
        }
        xg_cur = xg_nxt;
        bar_lgkm();   // B: h/c visible for next step
    }

    // ---- epilogue: feats from LDS h history -------------------------------
    for (int i = tid; i < 128 * 128; i += 512) {
        const int t = i >> 7, j = i & 127;
        const bool v = dir ? (t >= 128 - sl) : (t < sl);
        const float hv = v ? (float)hh[(size_t)(t + 1) * 128 + j] : 0.f;
        const int s = dir ? (127 - t) : t;
        feats[((size_t)b * 128 + s) * 256 + dir * 128 + j] = hv;
    }
}

// ---------------------------------------------------------------------------
// CRF: 2 batches per 64-thread block (one per 32-lane half). T columns in
// registers; alpha broadcast via LDS float4.
// ---------------------------------------------------------------------------
__global__ void crf_kernel(const float* __restrict__ logits,  // [B*S][32]
                           const int* __restrict__ label,     // [B*S]
                           const int* __restrict__ seqlen,
                           const float* __restrict__ T,       // [32][32]
                           float* __restrict__ out_part)      // [B]
{
    const int half = threadIdx.x >> 5;
    const int j    = threadIdx.x & 31;
    const int b    = blockIdx.x * 2 + half;

    float Tc[32];
#pragma unroll
    for (int i = 0; i < 32; ++i) Tc[i] = T[i * 32 + j];

    const float* lg = logits + (size_t)b * 128 * 32;
    const int* lab = label + b * 128;
    const int sl = seqlen[b];

    // gold score
    float g = 0.f;
#pragma unroll
    for (int r = 0; r < 4; ++r) {
        const int t = j + r * 32;
        if (t < sl) {
            g += lg[t * 32 + lab[t]];
            if (t >= 1) g += T[lab[t - 1] * 32 + lab[t]];
        }
    }
#pragma unroll
    for (int m = 16; m; m >>= 1) g += __shfl_xor(g, m, 32);

    __shared__ __align__(16) float alpha_s[2][32];
    float av = lg[j];
    alpha_s[half][j] = av;
    __syncthreads();
    for (int t = 1; t < 128; ++t) {
        float a[32];
        const float4* ap = (const float4*)alpha_s[half];
#pragma unroll
        for (int q = 0; q < 8; ++q) {
            const float4 v = ap[q];
            a[4 * q] = v.x; a[4 * q + 1] = v.y; a[4 * q + 2] = v.z; a[4 * q + 3] = v.w;
        }
        float m = -1e30f;
#pragma unroll
        for (int i = 0; i < 32; ++i) m = fmaxf(m, a[i] + Tc[i]);
        float s = 0.f;
#pragma unroll
        for (int i = 0; i < 32; ++i) s += __expf(a[i] + Tc[i] - m);
        float nv = m + __logf(s) + lg[t * 32 + j];
        if (t >= sl) nv = av;
        av = nv;
        __syncthreads();
        alpha_s[half][j] = av;
        __syncthreads();
    }
    // logZ over the half's 32 lanes
    float m2 = av;
#pragma unroll
    for (int m = 16; m; m >>= 1) m2 = fmaxf(m2, __shfl_xor(m2, m, 32));
    float s2 = __expf(av - m2);
#pragma unroll
    for (int m = 16; m; m >>= 1) s2 += __shfl_xor(s2, m, 32);
    if (j == 0) out_part[b] = (m2 + __logf(s2)) - g;
}

__global__ void finalize_kernel(const float* __restrict__ partb, float* __restrict__ out)
{
    if (threadIdx.x == 0 && blockIdx.x == 0) {
        float s = 0.f;
        for (int i = 0; i < 16; i++) s += partb[i];
        out[0] = s * (1.f / 16.f);
    }
}

extern "C" void kernel_launch(void* const* d_in, const int* in_sizes, int n_in,
                              void* d_out, int out_size, void* d_ws, size_t ws_size,
                              hipStream_t stream)
{
    (void)in_sizes; (void)n_in; (void)out_size; (void)ws_size;
    const int*   char_ids    = (const int*)d_in[0];
    const int*   kb_word_ids = (const int*)d_in[1];
    const int*   word_begin  = (const int*)d_in[2];
    const int*   word_len    = (const int*)d_in[3];
    const int*   label       = (const int*)d_in[4];
    const int*   seqlen      = (const int*)d_in[5];
    const float* char_emb    = (const float*)d_in[6];
    const float* kb_emb      = (const float*)d_in[7];
    const float* dense_W     = (const float*)d_in[8];
    const float* dense_b     = (const float*)d_in[9];
    const float* crf_T       = (const float*)d_in[10];
    const float* f_Wcx = (const float*)d_in[11];
    const float* f_Wch = (const float*)d_in[12];
    const float* f_bc  = (const float*)d_in[13];
    const float* f_Wwx = (const float*)d_in[14];
    const float* f_Wwh = (const float*)d_in[15];
    const float* f_bw  = (const float*)d_in[16];
    const float* f_Wlx = (const float*)d_in[17];
    const float* f_Wlc = (const float*)d_in[18];
    const float* f_bl  = (const float*)d_in[19];
    const float* r_Wcx = (const float*)d_in[20];
    const float* r_Wch = (const float*)d_in[21];
    const float* r_bc  = (const float*)d_in[22];
    const float* r_Wwx = (const float*)d_in[23];
    const float* r_Wwh = (const float*)d_in[24];
    const float* r_bw  = (const float*)d_in[25];
    const float* r_Wlx = (const float*)d_in[26];
    const float* r_Wlc = (const float*)d_in[27];
    const float* r_bl  = (const float*)d_in[28];

    float* ws = (float*)d_ws;
    size_t o = 0;
    float* Xg     = ws + o; o += (size_t)2 * 2048 * 512;   // [dir][B*S][512]
    float* Xl     = ws + o; o += (size_t)2 * 2048 * 128;   // [dir][B*S][128]
    float* Wg     = ws + o; o += (size_t)2 * 1024 * 384;   // [dir][B*N][384]
    float* feats  = ws + o; o += (size_t)2048 * 256;       // [B*S][2H]
    float* logits = ws + o; o += (size_t)2048 * 32;
    float* partb  = ws + o; o += 16;                       // ~16 MB total

    gemm_pair<128, 512, 8, 256><<<dim3(256, 2), 256, 0, stream>>>(
        char_emb, char_ids, f_Wcx, r_Wcx, f_bc, r_bc, Xg, 2048, 128, 1);
    gemm_pair<128, 128, 8, 256><<<dim3(256, 2), 256, 0, stream>>>(
        char_emb, char_ids, f_Wlx, r_Wlx, f_bl, r_bl, Xl, 2048, 128, 1);
    gemm_pair<128, 384, 8, 192><<<dim3(128, 2), 192, 0, stream>>>(
        kb_emb, kb_word_ids, f_Wwx, r_Wwx, f_bw, r_bw, Wg, 1024, 64, 0);

    lattice_kernel<<<32, 512, LAT_DYN_SMEM, stream>>>(
        Xg, Xl, Wg, f_Wch, r_Wch, f_Wwh, r_Wwh, f_Wlc, r_Wlc,
        word_begin, word_len, seqlen, feats);

    gemm_pair<256, 32, 16, 128><<<dim3(128, 1), 128, 0, stream>>>(
        feats, nullptr, dense_W, dense_W, dense_b, dense_b, logits, 2048, 128, 0);
    crf_kernel<<<8, 64, 0, stream>>>(logits, label, seqlen, crf_T, partb);
    finalize_kernel<<<1, 64, 0, stream>>>(partb, (float*)d_out);
}